// Round 2
// baseline (1340.154 us; speedup 1.0000x reference)
//
#include <hip/hip_runtime.h>
#include <cmath>

#define VOCAB 32000
#define EMB   256
#define HID   512
#define TLEN  513      // SEQ + 1
#define G4    2048     // 4*HID
#define NWG   32       // recurrence workgroups
#define SOS   1

typedef unsigned long long u64;

// ---------------------------------------------------------------------------
// Kernel A: Xg[t][r] = W_ih[r] . emb[tok_t] + b_ih[r] + b_hh[r]
// grid (33, 8), block 256. Block (bt,br): 16 timesteps x 256 gate rows.
// ---------------------------------------------------------------------------
__global__ __launch_bounds__(256) void precompute_gates(
    const int* __restrict__ seq, const float* __restrict__ emb,
    const float* __restrict__ W_ih, const float* __restrict__ b_ih,
    const float* __restrict__ b_hh, float* __restrict__ Xg)
{
    __shared__ __align__(16) float ebuf[16][EMB];
    const int bt = blockIdx.x;   // 0..32
    const int br = blockIdx.y;   // 0..7
    const int tid = threadIdx.x;

    for (int tt = 0; tt < 16; ++tt) {
        int t = bt * 16 + tt;
        if (t < TLEN) {
            int tok = (t == 0) ? SOS : seq[t - 1];
            ebuf[tt][tid] = emb[(size_t)tok * EMB + tid];
        }
    }
    __syncthreads();

    const int row = br * 256 + tid;
    float acc[16];
#pragma unroll
    for (int tt = 0; tt < 16; ++tt) acc[tt] = 0.f;

    const float4* wp = (const float4*)(W_ih + (size_t)row * EMB);
#pragma unroll 4
    for (int k4 = 0; k4 < EMB / 4; ++k4) {
        float4 w = wp[k4];
#pragma unroll
        for (int tt = 0; tt < 16; ++tt) {
            float4 e = *(const float4*)&ebuf[tt][k4 * 4];
            acc[tt] = fmaf(w.x, e.x, fmaf(w.y, e.y, fmaf(w.z, e.z, fmaf(w.w, e.w, acc[tt]))));
        }
    }

    const float bias = b_ih[row] + b_hh[row];
    for (int tt = 0; tt < 16; ++tt) {
        int t = bt * 16 + tt;
        if (t < TLEN) Xg[(size_t)t * G4 + row] = acc[tt] + bias;
    }
}

// ---------------------------------------------------------------------------
// Kernel B: persistent LSTM recurrence. 32 WGs x 256 threads.
// WG w owns h-indices [16w, 16w+16): gate rows q*512 + 16w + j, q in {i,f,g,o}.
// Cross-WG h broadcast: ONE 8-byte relaxed agent-scope atomic word per h elem,
// (tag = t+1) in high 32 bits, float bits in low 32. Tag+data are single-copy
// atomic together -> no fences / no separate flag needed. Double-buffered:
// h_t lives in pk[(t+1)&1][..]. pk is zeroed per launch (tags exact-match).
// ---------------------------------------------------------------------------
__global__ __launch_bounds__(256, 1) void lstm_recurrence(
    const float* __restrict__ Xg, const float* __restrict__ W_hh,
    const float* __restrict__ h0, const float* __restrict__ c0,
    float* __restrict__ hs, u64* pk,
    float* __restrict__ out_hT, float* __restrict__ out_cT)
{
    __shared__ __align__(16) float hbuf[HID];
    __shared__ float pbuf[256];
    __shared__ float gbuf[64];

    const int wg  = blockIdx.x;     // 0..31
    const int tid = threadIdx.x;
    const int wv  = tid >> 6;       // k segment 0..3
    const int ln  = tid & 63;       // local row 0..63
    const int q   = ln >> 4;
    const int j   = ln & 15;
    const int row = q * HID + wg * 16 + j;
    const int xrow = (tid < 64) ? ((tid >> 4) * HID + wg * 16 + (tid & 15)) : 0;

    // W_hh slice -> registers (32 float4 = 128 VGPRs)
    float4 wreg[32];
    const float4* wp = (const float4*)(W_hh + (size_t)row * HID + wv * 128);
#pragma unroll
    for (int i = 0; i < 32; ++i) wreg[i] = wp[i];

    float c = (tid < 16) ? c0[wg * 16 + tid] : 0.f;

    // h_{-1} = h0
    {
        float2 h2 = *(const float2*)&h0[tid * 2];
        hbuf[tid * 2]     = h2.x;
        hbuf[tid * 2 + 1] = h2.y;
    }
    __syncthreads();

    for (int t = 0; t < TLEN; ++t) {
        // issue Xg load early: completes under spin + matvec
        float xg = 0.f;
        if (tid < 64) xg = Xg[(size_t)t * G4 + xrow];

        if (t > 0) {
            const int s = t & 1;
            u64 w0, w1;
            do {
                w0 = __hip_atomic_load(&pk[s * HID + 2 * tid],
                                       __ATOMIC_RELAXED, __HIP_MEMORY_SCOPE_AGENT);
            } while ((unsigned)(w0 >> 32) != (unsigned)t);
            do {
                w1 = __hip_atomic_load(&pk[s * HID + 2 * tid + 1],
                                       __ATOMIC_RELAXED, __HIP_MEMORY_SCOPE_AGENT);
            } while ((unsigned)(w1 >> 32) != (unsigned)t);
            union { unsigned u; float f; } ua, ub;
            ua.u = (unsigned)w0;
            ub.u = (unsigned)w1;
            hbuf[2 * tid]     = ua.f;
            hbuf[2 * tid + 1] = ub.f;
            __syncthreads();
        }

        // partial matvec over my k segment, 8 independent accumulators
        float acc8[8];
#pragma unroll
        for (int i = 0; i < 8; ++i) acc8[i] = 0.f;
#pragma unroll
        for (int i = 0; i < 32; ++i) {
            float4 w  = wreg[i];
            float4 h4 = *(const float4*)&hbuf[wv * 128 + i * 4];
            acc8[i & 7] = fmaf(w.x, h4.x, fmaf(w.y, h4.y,
                          fmaf(w.z, h4.z, fmaf(w.w, h4.w, acc8[i & 7]))));
        }
        pbuf[tid] = ((acc8[0] + acc8[1]) + (acc8[2] + acc8[3]))
                  + ((acc8[4] + acc8[5]) + (acc8[6] + acc8[7]));
        __syncthreads();

        if (tid < 64) {
            gbuf[tid] = pbuf[tid] + pbuf[tid + 64] + pbuf[tid + 128] + pbuf[tid + 192] + xg;
        }
        __syncthreads();

        if (tid < 16) {
            float gi = gbuf[tid], gf = gbuf[16 + tid], gg = gbuf[32 + tid], go = gbuf[48 + tid];
            float i_ = 1.f / (1.f + expf(-gi));
            float f_ = 1.f / (1.f + expf(-gf));
            float g_ = tanhf(gg);
            float o_ = 1.f / (1.f + expf(-go));
            c = fmaf(f_, c, i_ * g_);
            float h_ = o_ * tanhf(c);
            hs[(size_t)t * HID + wg * 16 + tid] = h_;   // for out_gemm (kernel boundary)
            if (t < TLEN - 1) {
                union { float f; unsigned u; } hv; hv.f = h_;
                u64 word = ((u64)(unsigned)(t + 1) << 32) | (u64)hv.u;
                __hip_atomic_store(&pk[((t + 1) & 1) * HID + wg * 16 + tid], word,
                                   __ATOMIC_RELAXED, __HIP_MEMORY_SCOPE_AGENT);
            } else {
                out_hT[wg * 16 + tid] = h_;
                out_cT[wg * 16 + tid] = c;
            }
        }
        // hbuf of step t is free after the pbuf barrier; next-iter spin threads
        // may overwrite it, and the post-fill __syncthreads orders the matvec.
    }
}

// ---------------------------------------------------------------------------
// Kernel C: out[t][v] = hs[t] . W_out[v] + b_out[v]   (fp32 GEMM, B^T input)
// 128x128 tile, BK=32, 8x8 register tile, 256 threads. grid (250, 5).
// ---------------------------------------------------------------------------
#define BM 128
#define BN 128
#define BK 32
#define LDT (BK + 4)   // 36: float4-aligned pad

__global__ __launch_bounds__(256) void out_gemm(
    const float* __restrict__ hs, const float* __restrict__ W_out,
    const float* __restrict__ b_out, float* __restrict__ out)
{
    __shared__ __align__(16) float As[BM][LDT];
    __shared__ __align__(16) float Bs[BN][LDT];

    const int vb = blockIdx.x;     // 0..249
    const int tb = blockIdx.y;     // 0..4
    const int tid = threadIdx.x;
    const int tx = tid & 15;       // n group
    const int ty = tid >> 4;       // m group

    const int m0 = tb * BM, n0 = vb * BN;
    float acc[8][8];
#pragma unroll
    for (int i = 0; i < 8; ++i)
#pragma unroll
        for (int jj = 0; jj < 8; ++jj) acc[i][jj] = 0.f;

    for (int k0 = 0; k0 < HID; k0 += BK) {
#pragma unroll
        for (int it = 0; it < 4; ++it) {
            int li = tid + it * 256;        // 0..1023
            int m  = li >> 3;               // row 0..127
            int kq = li & 7;                // float4 index within BK
            int t  = m0 + m;
            float4 fa = (t < TLEN) ? *(const float4*)&hs[(size_t)t * HID + k0 + kq * 4]
                                   : make_float4(0.f, 0.f, 0.f, 0.f);
            *(float4*)&As[m][kq * 4] = fa;
            float4 fb = *(const float4*)&W_out[(size_t)(n0 + m) * HID + k0 + kq * 4];
            *(float4*)&Bs[m][kq * 4] = fb;
        }
        __syncthreads();

#pragma unroll
        for (int k = 0; k < BK; ++k) {
            float a[8], b[8];
#pragma unroll
            for (int i = 0; i < 8; ++i) a[i] = As[ty + 16 * i][k];
#pragma unroll
            for (int jj = 0; jj < 8; ++jj) b[jj] = Bs[tx + 16 * jj][k];
#pragma unroll
            for (int i = 0; i < 8; ++i)
#pragma unroll
                for (int jj = 0; jj < 8; ++jj)
                    acc[i][jj] = fmaf(a[i], b[jj], acc[i][jj]);
        }
        __syncthreads();
    }

#pragma unroll
    for (int jj = 0; jj < 8; ++jj) {
        int v = n0 + tx + 16 * jj;
        float bo = b_out[v];
#pragma unroll
        for (int i = 0; i < 8; ++i) {
            int t = m0 + ty + 16 * i;
            if (t < TLEN) out[(size_t)t * VOCAB + v] = acc[i][jj] + bo;
        }
    }
}

// ---------------------------------------------------------------------------
extern "C" void kernel_launch(void* const* d_in, const int* in_sizes, int n_in,
                              void* d_out, int out_size, void* d_ws, size_t ws_size,
                              hipStream_t stream)
{
    const int*   seq   = (const int*)  d_in[0];
    const float* h0    = (const float*)d_in[1];
    const float* c0    = (const float*)d_in[2];
    const float* emb   = (const float*)d_in[3];
    const float* W_ih  = (const float*)d_in[4];
    const float* W_hh  = (const float*)d_in[5];
    const float* b_ih  = (const float*)d_in[6];
    const float* b_hh  = (const float*)d_in[7];
    const float* W_out = (const float*)d_in[8];
    const float* b_out = (const float*)d_in[9];

    float* out_logits = (float*)d_out;                      // [513][32000]
    float* out_hT     = out_logits + (size_t)TLEN * VOCAB;  // [512]
    float* out_cT     = out_hT + HID;                       // [512]

    float* Xg = (float*)d_ws;                    // 513*2048 floats
    float* hs = Xg + (size_t)TLEN * G4;          // 513*512 floats
    u64*   pk = (u64*)(hs + (size_t)TLEN * HID); // [2][512] packed tag|h words

    hipMemsetAsync(pk, 0, 2 * HID * sizeof(u64), stream);
    precompute_gates<<<dim3(33, 8), 256, 0, stream>>>(seq, emb, W_ih, b_ih, b_hh, Xg);
    lstm_recurrence<<<NWG, 256, 0, stream>>>(Xg, W_hh, h0, c0, hs, pk, out_hT, out_cT);
    out_gemm<<<dim3(250, 5), 256, 0, stream>>>(hs, W_out, b_out, out_logits);
}